// Round 2
// baseline (410.397 us; speedup 1.0000x reference)
//
#include <hip/hip_runtime.h>
#include <math.h>

#define NTOK 4096
#define DDIM 1024
#define HDIM 4096
#define NEXP 8
#define BK 64

typedef float f32x4 __attribute__((ext_vector_type(4)));
typedef __bf16 bf16x8 __attribute__((ext_vector_type(8)));
typedef const __attribute__((address_space(1))) void gas_t;
typedef __attribute__((address_space(3))) void las_t;

__device__ __forceinline__ unsigned short f2bf(float f) {
    union { float f; unsigned u; } v; v.f = f;
    unsigned u = v.u;
    return (unsigned short)((u + 0x7fffu + ((u >> 16) & 1u)) >> 16);
}

__device__ __forceinline__ float gelu_f(float v) {
    return 0.5f * v * (1.0f + erff(v * 0.70710678118654752f));
}

// ---------------- gating: one wave per token (also emits xb = bf16(x)) ----------------
__global__ void k_gate(const float* __restrict__ x, const float* __restrict__ gw,
                       const float* __restrict__ gb, unsigned short* __restrict__ xb,
                       int* __restrict__ sel, int* __restrict__ counts) {
    const int wid = threadIdx.x >> 6, lane = threadIdx.x & 63;
    const int tok = blockIdx.x * 4 + wid;
    const float* xr = x + (long)tok * DDIM;
    unsigned short* xbr = xb + (long)tok * DDIM;
    float s[NEXP];
#pragma unroll
    for (int e = 0; e < NEXP; ++e) s[e] = 0.f;
    for (int it = 0; it < DDIM / 64; ++it) {
        const int kk = it * 64 + lane;
        const float xv = xr[kk];
        xbr[kk] = f2bf(xv);
        const float4* g4 = (const float4*)(gw + (long)kk * NEXP);
        const float4 g0 = g4[0], g1 = g4[1];
        s[0] += xv * g0.x; s[1] += xv * g0.y; s[2] += xv * g0.z; s[3] += xv * g0.w;
        s[4] += xv * g1.x; s[5] += xv * g1.y; s[6] += xv * g1.z; s[7] += xv * g1.w;
    }
#pragma unroll
    for (int e = 0; e < NEXP; ++e)
        for (int off = 32; off > 0; off >>= 1)
            s[e] += __shfl_down(s[e], off);
    if (lane == 0) {
        float best = s[0] + gb[0]; int bi = 0;
#pragma unroll
        for (int e = 1; e < NEXP; ++e) {
            const float v = s[e] + gb[e];
            if (v > best) { best = v; bi = e; }   // strict > keeps lowest index (np.argmax)
        }
        sel[tok] = bi;
        atomicAdd(&counts[bi], 1);
    }
}

// ---------------- scan (tiny) ----------------
__global__ void k_scan(const int* __restrict__ counts, int* __restrict__ offs,
                       int* __restrict__ cursors, float* __restrict__ laux) {
    if (threadIdx.x == 0 && blockIdx.x == 0) {
        int o = 0;
        for (int e = 0; e < NEXP; ++e) { offs[e] = o; cursors[e] = o; o += counts[e]; }
        offs[NEXP] = o;
        laux[0] = 0.f;
    }
}

// ---------------- fill token lists ----------------
__global__ void k_fill(const int* __restrict__ sel, int* __restrict__ cursors,
                       int* __restrict__ list) {
    const int t = blockIdx.x * blockDim.x + threadIdx.x;
    if (t < NTOK) {
        const int e = sel[t];
        const int slot = atomicAdd(&cursors[e], 1);
        list[slot] = t;
    }
}

// ---------------- W [e][K][NC] f32 -> Wt [e][NC][K] bf16 (transpose-convert) ----------------
template<int K, int NC>
__global__ __launch_bounds__(256) void k_cvt_w(const float* __restrict__ W,
                                               unsigned short* __restrict__ Wt) {
    __shared__ unsigned short T[64 * 68];   // [n][k], stride 68 breaks bank conflicts
    const int ktiles = K / 64;
    const int e  = blockIdx.y / ktiles;
    const int k0 = (blockIdx.y % ktiles) * 64;
    const int n0 = blockIdx.x * 64;
    const float* src = W + (long)e * K * NC + (long)k0 * NC + n0;
    const int tid = threadIdx.x;
#pragma unroll
    for (int i = 0; i < 4; ++i) {
        const int idx = tid + i * 256;
        const int k = idx >> 4, c4 = (idx & 15) * 4;
        const float4 v = *(const float4*)(src + (long)k * NC + c4);
        T[(c4 + 0) * 68 + k] = f2bf(v.x);
        T[(c4 + 1) * 68 + k] = f2bf(v.y);
        T[(c4 + 2) * 68 + k] = f2bf(v.z);
        T[(c4 + 3) * 68 + k] = f2bf(v.w);
    }
    __syncthreads();
    unsigned short* dst = Wt + (long)e * NC * K + (long)n0 * K + k0;
#pragma unroll
    for (int i = 0; i < 2; ++i) {
        const int idx = tid + i * 256;
        const int n = idx >> 3, c8 = (idx & 7) * 8;
        *(ushort4*)(dst + (long)n * K + c8)     = *(const ushort4*)&T[n * 68 + c8];
        *(ushort4*)(dst + (long)n * K + c8 + 4) = *(const ushort4*)&T[n * 68 + c8 + 4];
    }
}

// ---------------- grouped GEMM, 8-phase counted-vmcnt schedule ----------------
// 512 threads = 8 waves; per-wave output 64x64; 4 phases per K-tile (quadrant snake).
// LDS: double-buffered A[BM][64] + B[BN][64] bf16, XOR-swizzled via pre-swizzled global src.
// Issue slots: tile T's halves staged at (T-2,ph3)=Ba, (T-2,ph4)=Aa, (T-1,ph1)=Bb, (T-1,ph2)=Ab.
// Boundary s_waitcnt vmcnt(3) leaves exactly the next-next tile's LA+LB loads in flight.
template<int MODE, int BM_, int BN_, int SK>
__global__ __launch_bounds__(512, 2) void k_gemm8(
        const unsigned short* __restrict__ Ain,
        const unsigned short* __restrict__ Wt,
        const float* __restrict__ bias,
        unsigned short* __restrict__ Hout, float* __restrict__ Yout,
        const int* __restrict__ counts, const int* __restrict__ offs,
        const int* __restrict__ list) {
    constexpr int K  = (MODE == 0) ? DDIM : HDIM;
    constexpr int NC = (MODE == 0) ? HDIM : DDIM;
    constexpr int KP = K / SK;           // K span per split part
    constexpr int NT = KP / BK;          // K-tiles per block
    constexpr int MT = NTOK / BM_;
    constexpr int WN = (MODE == 0) ? 4 : 2;   // wave grid: (8/WN) x WN, per-wave 64x64
    constexpr int LA = BM_ / 128;        // global_load_lds per thread per A-half
    constexpr int LB = BN_ / 128;
    static_assert(LA + LB == 3, "vmcnt immediates assume LA+LB==3");

    const int by  = blockIdx.y;
    const int e   = by / (MT * SK);
    const int rem = by % (MT * SK);
    const int mt  = rem / SK;
    const int sk  = rem % SK;
    const int cnt = counts[e];
    const int m0  = mt * BM_;
    if (m0 >= cnt) return;
    const int base = offs[e];
    const int n0   = blockIdx.x * BN_;

    __shared__ __align__(16) unsigned short As[2][BM_ * 64];
    __shared__ __align__(16) unsigned short Bs[2][BN_ * 64];

    const int tid  = threadIdx.x;
    const int lane = tid & 63, wid = tid >> 6;
    const int lr = lane >> 3, lc = lane & 7;
    const int sb = (lc * 16) ^ (lr << 4);       // pre-swizzled source byte offset

    // staging source pointers (row&7 == lr, so XOR pattern is loop-invariant)
    const unsigned short* pA[2 * LA];
#pragma unroll
    for (int h = 0; h < 2; ++h)
#pragma unroll
        for (int j = 0; j < LA; ++j) {
            const int r = h * (BM_ / 2) + j * 64 + wid * 8 + lr;
            int rr = m0 + r; if (rr >= cnt) rr = cnt - 1;
            const long grow = (MODE == 0) ? (long)list[base + rr] : (long)(base + rr);
            pA[h * LA + j] = (const unsigned short*)(
                (const char*)(Ain + grow * K + (long)sk * KP) + sb);
        }
    const unsigned short* We = Wt + (long)e * NC * K;
    const unsigned short* pB[2 * LB];
#pragma unroll
    for (int h = 0; h < 2; ++h)
#pragma unroll
        for (int j = 0; j < LB; ++j) {
            const int r = h * (BN_ / 2) + j * 64 + wid * 8 + lr;
            pB[h * LB + j] = (const unsigned short*)(
                (const char*)(We + (long)(n0 + r) * K + (long)sk * KP) + sb);
        }

    const int wm = (wid / WN) * 64;
    const int wn = (wid % WN) * 64;
    const int hk = 16 * (lane >> 4);

#define STAGE_A(h, t) do { if ((t) < NT) { const int _b = (t) & 1;                       \
    _Pragma("unroll") for (int j = 0; j < LA; ++j)                                       \
        __builtin_amdgcn_global_load_lds((gas_t*)(pA[(h) * LA + j] + (t) * 64),          \
            (las_t*)(&As[_b][((h) * (BM_ / 2) + j * 64 + wid * 8) * 64]), 16, 0, 0); } } while (0)
#define STAGE_B(h, t) do { if ((t) < NT) { const int _b = (t) & 1;                       \
    _Pragma("unroll") for (int j = 0; j < LB; ++j)                                       \
        __builtin_amdgcn_global_load_lds((gas_t*)(pB[(h) * LB + j] + (t) * 64),          \
            (las_t*)(&Bs[_b][((h) * (BN_ / 2) + j * 64 + wid * 8) * 64]), 16, 0, 0); } } while (0)
#define LDA_Q(qm, areg) do {                                                             \
    _Pragma("unroll") for (int mf = 0; mf < 2; ++mf)                                     \
    _Pragma("unroll") for (int k2 = 0; k2 < 2; ++k2) {                                   \
        const int r  = wm + (qm) * 32 + mf * 16 + (lane & 15);                           \
        const int kb = (k2 * 64 + hk) ^ ((r & 7) << 4);                                  \
        areg[mf * 2 + k2] = *(const bf16x8*)((const char*)&As[bs][0] + r * 128 + kb); } } while (0)
#define LDB_Q(qn, breg) do {                                                             \
    _Pragma("unroll") for (int nf = 0; nf < 2; ++nf)                                     \
    _Pragma("unroll") for (int k2 = 0; k2 < 2; ++k2) {                                   \
        const int c  = wn + (qn) * 32 + nf * 16 + (lane & 15);                           \
        const int kb = (k2 * 64 + hk) ^ ((c & 7) << 4);                                  \
        breg[nf * 2 + k2] = *(const bf16x8*)((const char*)&Bs[bs][0] + c * 128 + kb); } } while (0)
#define MFMA_Q(qm, qn, areg, breg) do {                                                  \
    __builtin_amdgcn_s_setprio(1);                                                       \
    _Pragma("unroll") for (int k2 = 0; k2 < 2; ++k2)                                     \
    _Pragma("unroll") for (int mf = 0; mf < 2; ++mf)                                     \
    _Pragma("unroll") for (int nf = 0; nf < 2; ++nf)                                     \
        acc[(qm) * 2 + mf][(qn) * 2 + nf] = __builtin_amdgcn_mfma_f32_16x16x32_bf16(     \
            areg[mf * 2 + k2], breg[nf * 2 + k2], acc[(qm) * 2 + mf][(qn) * 2 + nf],     \
            0, 0, 0);                                                                    \
    __builtin_amdgcn_s_setprio(0); } while (0)
#define BAR() __builtin_amdgcn_s_barrier()
#define LGKM0() do { asm volatile("s_waitcnt lgkmcnt(0)" ::: "memory");                  \
    __builtin_amdgcn_sched_barrier(0); } while (0)

    const f32x4 zero4 = {0.f, 0.f, 0.f, 0.f};
    f32x4 acc[4][4];
#pragma unroll
    for (int i = 0; i < 4; ++i)
#pragma unroll
        for (int j = 0; j < 4; ++j) acc[i][j] = zero4;

    // prologue: tile0 fully + tile1's (Ba, Aa) slots
    STAGE_B(0, 0); STAGE_A(0, 0); STAGE_B(1, 0); STAGE_A(1, 0);
    STAGE_B(0, 1); STAGE_A(0, 1);
    asm volatile("s_waitcnt vmcnt(3)" ::: "memory");
    __builtin_amdgcn_sched_barrier(0);
    BAR();

    bf16x8 a[4], b0[4], b1[4];
    for (int t = 0; t < NT; ++t) {
        const int bs = t & 1;
        // phase 1: q(0,0); issue Bb(t+1)
        LDA_Q(0, a); LDB_Q(0, b0);
        STAGE_B(1, t + 1);
        BAR(); LGKM0();
        MFMA_Q(0, 0, a, b0);
        BAR();
        // phase 2: q(0,1); issue Ab(t+1)
        LDB_Q(1, b1);
        STAGE_A(1, t + 1);
        BAR(); LGKM0();
        MFMA_Q(0, 1, a, b1);
        BAR();
        // phase 3: q(1,1); issue Ba(t+2)  (tile t's B reads all done after phase 2)
        LDA_Q(1, a);
        STAGE_B(0, t + 2);
        BAR(); LGKM0();
        MFMA_Q(1, 1, a, b1);
        BAR();
        // phase 4: q(1,0); issue Aa(t+2)  (tile t's A reads all done after phase 3)
        STAGE_A(0, t + 2);
        if (t + 2 < NT) { asm volatile("s_waitcnt vmcnt(3)" ::: "memory"); }
        else            { asm volatile("s_waitcnt vmcnt(0)" ::: "memory"); }
        __builtin_amdgcn_sched_barrier(0);
        BAR();
        MFMA_Q(1, 0, a, b0);
        BAR();
    }
#undef STAGE_A
#undef STAGE_B
#undef LDA_Q
#undef LDB_Q
#undef MFMA_Q
#undef BAR
#undef LGKM0

    // ---- epilogue ----
#pragma unroll
    for (int j = 0; j < 4; ++j) {
        const int col = n0 + wn + j * 16 + (lane & 15);
        const float bv = bias[(long)e * NC + col];
#pragma unroll
        for (int i = 0; i < 4; ++i) {
            const int rb = m0 + wm + i * 16 + (lane >> 4) * 4;
#pragma unroll
            for (int ri = 0; ri < 4; ++ri) {
                const int row = rb + ri;
                if (row < cnt) {
                    if constexpr (MODE == 0) {
                        const float v = acc[i][j][ri] + bv;
                        Hout[(long)(base + row) * HDIM + col] = f2bf(gelu_f(v));
                    } else {
                        const float v = acc[i][j][ri] + (sk == 0 ? bv : 0.f);
                        atomicAdd(&Yout[(long)list[base + row] * DDIM + col], v);
                    }
                }
            }
        }
    }
}

extern "C" void kernel_launch(void* const* d_in, const int* in_sizes, int n_in,
                              void* d_out, int out_size, void* d_ws, size_t ws_size,
                              hipStream_t stream) {
    const float* x      = (const float*)d_in[0];
    const float* gate_w = (const float*)d_in[1];
    const float* gate_b = (const float*)d_in[2];
    const float* w1     = (const float*)d_in[3];
    const float* b1     = (const float*)d_in[4];
    const float* w2     = (const float*)d_in[5];
    const float* b2     = (const float*)d_in[6];
    float* out = (float*)d_out;

    // workspace layout
    char* ws = (char*)d_ws;
    int* counts  = (int*)(ws);                 // 8
    int* cursors = (int*)(ws + 128);           // 8
    int* offs    = (int*)(ws + 256);           // 9
    int* sel     = (int*)(ws + 1024);          // 4096
    int* list    = (int*)(ws + 1024 + 16384);  // 4096
    unsigned short* xb  = (unsigned short*)(ws + 65536);                      // 8 MB
    unsigned short* Hws = (unsigned short*)(ws + 65536 + 8388608);            // 33.5 MB
    unsigned short* Wtb = (unsigned short*)(ws + 65536 + 8388608 + 33554432); // 67 MB (W1t then W2t)
    const size_t WS_NEEDED = 65536 + 8388608 + 33554432 + 67108864;
    if (ws_size < WS_NEEDED) return;  // deterministic fail, no corruption

    hipMemsetAsync(ws, 0, 1024, stream);
    hipMemsetAsync(out, 0, (size_t)NTOK * DDIM * sizeof(float), stream);  // split-K accum base
    k_gate<<<NTOK / 4, 256, 0, stream>>>(x, gate_w, gate_b, xb, sel, counts);
    k_scan<<<1, 64, 0, stream>>>(counts, offs, cursors, out + (long)NTOK * DDIM);
    k_fill<<<(NTOK + 255) / 256, 256, 0, stream>>>(sel, cursors, list);

    // W1t = transpose-convert(w1); FFN up+gelu: 128x256 tiles, 8-phase
    k_cvt_w<DDIM, HDIM><<<dim3(HDIM / 64, NEXP * (DDIM / 64)), 256, 0, stream>>>(w1, Wtb);
    k_gemm8<0, 128, 256, 1><<<dim3(HDIM / 256, NEXP * (NTOK / 128)), 512, 0, stream>>>(
        xb, Wtb, b1, Hws, nullptr, counts, offs, list);

    // W2t = transpose-convert(w2) into same buffer; FFN down: 256x128 tiles, split-K=2
    k_cvt_w<HDIM, DDIM><<<dim3(DDIM / 64, NEXP * (HDIM / 64)), 256, 0, stream>>>(w2, Wtb);
    k_gemm8<1, 256, 128, 2><<<dim3(DDIM / 128, NEXP * (NTOK / 256) * 2), 512, 0, stream>>>(
        Hws, Wtb, b2, nullptr, out, counts, offs, list);
}

// Round 3
// 313.747 us; speedup vs baseline: 1.3081x; 1.3081x over previous
//
#include <hip/hip_runtime.h>
#include <math.h>

#define NTOK 4096
#define DDIM 1024
#define HDIM 4096
#define NEXP 8
#define BK 64

typedef float f32x4 __attribute__((ext_vector_type(4)));
typedef __bf16 bf16x8 __attribute__((ext_vector_type(8)));
typedef const __attribute__((address_space(1))) void gas_t;
typedef __attribute__((address_space(3))) void las_t;

__device__ __forceinline__ unsigned short f2bf(float f) {
    union { float f; unsigned u; } v; v.f = f;
    unsigned u = v.u;
    return (unsigned short)((u + 0x7fffu + ((u >> 16) & 1u)) >> 16);
}

__device__ __forceinline__ float gelu_f(float v) {
    return 0.5f * v * (1.0f + erff(v * 0.70710678118654752f));
}

// ---------------- gating: one wave per token (also emits xb = bf16(x)) ----------------
__global__ void k_gate(const float* __restrict__ x, const float* __restrict__ gw,
                       const float* __restrict__ gb, unsigned short* __restrict__ xb,
                       int* __restrict__ sel, int* __restrict__ counts) {
    const int wid = threadIdx.x >> 6, lane = threadIdx.x & 63;
    const int tok = blockIdx.x * 4 + wid;
    const float* xr = x + (long)tok * DDIM;
    unsigned short* xbr = xb + (long)tok * DDIM;
    float s[NEXP];
#pragma unroll
    for (int e = 0; e < NEXP; ++e) s[e] = 0.f;
    for (int it = 0; it < DDIM / 64; ++it) {
        const int kk = it * 64 + lane;
        const float xv = xr[kk];
        xbr[kk] = f2bf(xv);
        const float4* g4 = (const float4*)(gw + (long)kk * NEXP);
        const float4 g0 = g4[0], g1 = g4[1];
        s[0] += xv * g0.x; s[1] += xv * g0.y; s[2] += xv * g0.z; s[3] += xv * g0.w;
        s[4] += xv * g1.x; s[5] += xv * g1.y; s[6] += xv * g1.z; s[7] += xv * g1.w;
    }
#pragma unroll
    for (int e = 0; e < NEXP; ++e)
        for (int off = 32; off > 0; off >>= 1)
            s[e] += __shfl_down(s[e], off);
    if (lane == 0) {
        float best = s[0] + gb[0]; int bi = 0;
#pragma unroll
        for (int e = 1; e < NEXP; ++e) {
            const float v = s[e] + gb[e];
            if (v > best) { best = v; bi = e; }   // strict > keeps lowest index (np.argmax)
        }
        sel[tok] = bi;
        atomicAdd(&counts[bi], 1);
    }
}

// ---------------- scan (tiny) ----------------
__global__ void k_scan(const int* __restrict__ counts, int* __restrict__ offs,
                       int* __restrict__ cursors, float* __restrict__ laux) {
    if (threadIdx.x == 0 && blockIdx.x == 0) {
        int o = 0;
        for (int e = 0; e < NEXP; ++e) { offs[e] = o; cursors[e] = o; o += counts[e]; }
        offs[NEXP] = o;
        laux[0] = 0.f;
    }
}

// ---------------- fill token lists ----------------
__global__ void k_fill(const int* __restrict__ sel, int* __restrict__ cursors,
                       int* __restrict__ list) {
    const int t = blockIdx.x * blockDim.x + threadIdx.x;
    if (t < NTOK) {
        const int e = sel[t];
        const int slot = atomicAdd(&cursors[e], 1);
        list[slot] = t;
    }
}

// ---------------- W [e][K][NC] f32 -> Wt [e][NC][K] bf16 (transpose-convert) ----------------
template<int K, int NC>
__global__ __launch_bounds__(256) void k_cvt_w(const float* __restrict__ W,
                                               unsigned short* __restrict__ Wt) {
    __shared__ unsigned short T[64 * 68];   // [n][k], stride 68 breaks bank conflicts
    const int ktiles = K / 64;
    const int e  = blockIdx.y / ktiles;
    const int k0 = (blockIdx.y % ktiles) * 64;
    const int n0 = blockIdx.x * 64;
    const float* src = W + (long)e * K * NC + (long)k0 * NC + n0;
    const int tid = threadIdx.x;
#pragma unroll
    for (int i = 0; i < 4; ++i) {
        const int idx = tid + i * 256;
        const int k = idx >> 4, c4 = (idx & 15) * 4;
        const float4 v = *(const float4*)(src + (long)k * NC + c4);
        T[(c4 + 0) * 68 + k] = f2bf(v.x);
        T[(c4 + 1) * 68 + k] = f2bf(v.y);
        T[(c4 + 2) * 68 + k] = f2bf(v.z);
        T[(c4 + 3) * 68 + k] = f2bf(v.w);
    }
    __syncthreads();
    unsigned short* dst = Wt + (long)e * NC * K + (long)n0 * K + k0;
#pragma unroll
    for (int i = 0; i < 2; ++i) {
        const int idx = tid + i * 256;
        const int n = idx >> 3, c8 = (idx & 7) * 8;
        *(ushort4*)(dst + (long)n * K + c8)     = *(const ushort4*)&T[n * 68 + c8];
        *(ushort4*)(dst + (long)n * K + c8 + 4) = *(const ushort4*)&T[n * 68 + c8 + 4];
    }
}

// ---------------- grouped GEMM: m97 structure + 2-phase dbuf + XCD-affinity swizzle ----
// 256 threads = 4 waves; per-wave output (BM/2)x64. Double-buffered LDS, XOR swizzle via
// pre-swizzled global source. One __syncthreads per K-tile: STAGE(t+1) issued BEFORE the
// ds_read/MFMA of tile t, so next-tile latency hides under compute (T3-minimum recipe).
// Block decode puts all mt-tiles of one (expert, col) panel on the SAME XCD consecutively
// so weight-panel re-reads hit that XCD's L2 (T1 mechanism on the reused operand).
template<int MODE, int BM_, int BN_>
__global__ __launch_bounds__(256) void k_gemm(
        const unsigned short* __restrict__ Ain,
        const unsigned short* __restrict__ Wt,
        const float* __restrict__ bias,
        unsigned short* __restrict__ Hout, float* __restrict__ Yout,
        const int* __restrict__ counts, const int* __restrict__ offs,
        const int* __restrict__ list) {
    static_assert(BM_ % 32 == 0 && BN_ % 32 == 0, "tile");
    constexpr int K    = (MODE == 0) ? DDIM : HDIM;
    constexpr int NC   = (MODE == 0) ? HDIM : DDIM;
    constexpr int NT   = K / BK;
    constexpr int MT   = NTOK / BM_;
    constexpr int COLS = NC / BN_;
    constexpr int FM   = BM_ / 32;
    constexpr int FN   = BN_ / 32;
    constexpr int LA   = BM_ / 32;   // A loads per thread per tile
    constexpr int LB   = BN_ / 32;

    // ---- XCD-affinity decode: same (e,col) -> same XCD, mt fastest within it ----
    const int FLAT = blockIdx.y * COLS + blockIdx.x;
    const int xcd = FLAT & 7;
    const int c   = FLAT >> 3;
    const int mt  = c % MT;
    const int p   = xcd + 8 * (c / MT);          // (e,col) pair id
    const int e   = p / COLS;
    const int col = p % COLS;

    const int cnt = counts[e];
    const int m0  = mt * BM_;
    if (m0 >= cnt) return;
    const int base = offs[e];
    const int n0   = col * BN_;

    __shared__ __align__(16) unsigned short As[2][BM_ * 64];
    __shared__ __align__(16) unsigned short Bt[2][BN_ * 64];

    const int tid  = threadIdx.x;
    const int lane = tid & 63, wid = tid >> 6;
    const int lr = lane >> 3, lc = lane & 7;
    const int sb = (lc * 16) ^ (lr << 4);        // pre-swizzled source byte offset

    // per-lane global source pointers (row&7 == lr, so XOR pattern is loop-invariant)
    const unsigned short* pA[LA];
#pragma unroll
    for (int i = 0; i < LA; ++i) {
        const int r = wid * (BM_ / 4) + i * 8 + lr;
        int rr = m0 + r; if (rr >= cnt) rr = cnt - 1;
        const long grow = (MODE == 0) ? (long)list[base + rr] : (long)(base + rr);
        pA[i] = (const unsigned short*)((const char*)(Ain + grow * K) + sb);
    }
    const unsigned short* We = Wt + (long)e * NC * K;
    const unsigned short* pB[LB];
#pragma unroll
    for (int i = 0; i < LB; ++i) {
        const int r = wid * (BN_ / 4) + i * 8 + lr;
        pB[i] = (const unsigned short*)((const char*)(We + (long)(n0 + r) * K) + sb);
    }

    const int wm = (wid >> 1) * (BM_ / 2);
    const int wn = (wid & 1) * 64;
    const int hk = 16 * (lane >> 4);

#define STAGE(t) do { const int _b = (t) & 1;                                            \
    _Pragma("unroll") for (int i = 0; i < LA; ++i)                                       \
        __builtin_amdgcn_global_load_lds((gas_t*)(pA[i] + (t) * 64),                     \
            (las_t*)(&As[_b][(wid * (BM_ / 4) + i * 8) * 64]), 16, 0, 0);                \
    _Pragma("unroll") for (int i = 0; i < LB; ++i)                                       \
        __builtin_amdgcn_global_load_lds((gas_t*)(pB[i] + (t) * 64),                     \
            (las_t*)(&Bt[_b][(wid * (BN_ / 4) + i * 8) * 64]), 16, 0, 0); } while (0)

    const f32x4 zero4 = {0.f, 0.f, 0.f, 0.f};
    f32x4 acc[FM][FN];
#pragma unroll
    for (int i = 0; i < FM; ++i)
#pragma unroll
        for (int j = 0; j < FN; ++j) acc[i][j] = zero4;

    STAGE(0);
    __syncthreads();

    for (int t = 0; t < NT; ++t) {
        const int bs = t & 1;
        if (t + 1 < NT) STAGE(t + 1);            // prefetch into other buffer
#pragma unroll
        for (int kk = 0; kk < BK; kk += 32) {
            bf16x8 a[FM], b[FN];
#pragma unroll
            for (int mf = 0; mf < FM; ++mf) {
                const int r  = wm + mf * 16 + (lane & 15);
                const int kb = (2 * kk + hk) ^ ((r & 7) << 4);
                a[mf] = *(const bf16x8*)((const char*)&As[bs][0] + r * 128 + kb);
            }
#pragma unroll
            for (int nf = 0; nf < FN; ++nf) {
                const int cc = wn + nf * 16 + (lane & 15);
                const int kb = (2 * kk + hk) ^ ((cc & 7) << 4);
                b[nf] = *(const bf16x8*)((const char*)&Bt[bs][0] + cc * 128 + kb);
            }
            __builtin_amdgcn_s_setprio(1);
#pragma unroll
            for (int mf = 0; mf < FM; ++mf)
#pragma unroll
                for (int nf = 0; nf < FN; ++nf)
                    acc[mf][nf] = __builtin_amdgcn_mfma_f32_16x16x32_bf16(
                        a[mf], b[nf], acc[mf][nf], 0, 0, 0);
            __builtin_amdgcn_s_setprio(0);
        }
        __syncthreads();   // drains own vmcnt+lgkm; prefetch landed, everyone done reading bs
    }
#undef STAGE

    // ---- epilogue ----
#pragma unroll
    for (int nf = 0; nf < FN; ++nf) {
        const int coln = n0 + wn + nf * 16 + (lane & 15);
        const float bv = bias[(long)e * NC + coln];
#pragma unroll
        for (int mf = 0; mf < FM; ++mf) {
            const int rb = m0 + wm + mf * 16 + (lane >> 4) * 4;
#pragma unroll
            for (int ri = 0; ri < 4; ++ri) {
                const int row = rb + ri;
                if (row < cnt) {
                    const float v = acc[mf][nf][ri] + bv;
                    if constexpr (MODE == 0)
                        Hout[(long)(base + row) * HDIM + coln] = f2bf(gelu_f(v));
                    else
                        Yout[(long)list[base + row] * DDIM + coln] = v;
                }
            }
        }
    }
}

extern "C" void kernel_launch(void* const* d_in, const int* in_sizes, int n_in,
                              void* d_out, int out_size, void* d_ws, size_t ws_size,
                              hipStream_t stream) {
    const float* x      = (const float*)d_in[0];
    const float* gate_w = (const float*)d_in[1];
    const float* gate_b = (const float*)d_in[2];
    const float* w1     = (const float*)d_in[3];
    const float* b1     = (const float*)d_in[4];
    const float* w2     = (const float*)d_in[5];
    const float* b2     = (const float*)d_in[6];
    float* out = (float*)d_out;

    // workspace layout
    char* ws = (char*)d_ws;
    int* counts  = (int*)(ws);                 // 8
    int* cursors = (int*)(ws + 128);           // 8
    int* offs    = (int*)(ws + 256);           // 9
    int* sel     = (int*)(ws + 1024);          // 4096
    int* list    = (int*)(ws + 1024 + 16384);  // 4096
    unsigned short* xb  = (unsigned short*)(ws + 65536);                      // 8 MB
    unsigned short* Hws = (unsigned short*)(ws + 65536 + 8388608);            // 33.5 MB
    unsigned short* Wtb = (unsigned short*)(ws + 65536 + 8388608 + 33554432); // 67 MB (W1t then W2t)
    const size_t WS_NEEDED = 65536 + 8388608 + 33554432 + 67108864;
    if (ws_size < WS_NEEDED) return;  // deterministic fail, no corruption

    hipMemsetAsync(ws, 0, 1024, stream);
    k_gate<<<NTOK / 4, 256, 0, stream>>>(x, gate_w, gate_b, xb, sel, counts);
    k_scan<<<1, 64, 0, stream>>>(counts, offs, cursors, out + (long)NTOK * DDIM);
    k_fill<<<(NTOK + 255) / 256, 256, 0, stream>>>(sel, cursors, list);

    // W1t = transpose-convert(w1); FFN up+gelu: 128x128 tiles, 2-phase dbuf
    k_cvt_w<DDIM, HDIM><<<dim3(HDIM / 64, NEXP * (DDIM / 64)), 256, 0, stream>>>(w1, Wtb);
    k_gemm<0, 128, 128><<<dim3(HDIM / 128, NEXP * (NTOK / 128)), 256, 0, stream>>>(
        xb, Wtb, b1, Hws, nullptr, counts, offs, list);

    // W2t = transpose-convert(w2) into same buffer; FFN down: 64x128 tiles, 2-phase dbuf
    k_cvt_w<HDIM, DDIM><<<dim3(DDIM / 64, NEXP * (HDIM / 64)), 256, 0, stream>>>(w2, Wtb);
    k_gemm<1, 64, 128><<<dim3(DDIM / 128, NEXP * (NTOK / 64)), 256, 0, stream>>>(
        Hws, Wtb, b2, nullptr, out, counts, offs, list);
}

// Round 5
// 279.789 us; speedup vs baseline: 1.4668x; 1.1214x over previous
//
#include <hip/hip_runtime.h>
#include <math.h>

#define NTOK 4096
#define DDIM 1024
#define HDIM 4096
#define NEXP 8
#define BK 64
#define T0MAX 40   // >= NTOK/128 + NEXP-1 live tiles for GEMM0
#define T1MAX 72   // >= NTOK/64  + NEXP-1 live tiles for GEMM1

typedef float f32x4 __attribute__((ext_vector_type(4)));
typedef __bf16 bf16x8 __attribute__((ext_vector_type(8)));
typedef const __attribute__((address_space(1))) void gas_t;
typedef __attribute__((address_space(3))) void las_t;

__device__ __forceinline__ unsigned short f2bf(float f) {
    union { float f; unsigned u; } v; v.f = f;
    unsigned u = v.u;
    return (unsigned short)((u + 0x7fffu + ((u >> 16) & 1u)) >> 16);
}

__device__ __forceinline__ float gelu_f(float v) {
    return 0.5f * v * (1.0f + erff(v * 0.70710678118654752f));
}

// ---------------- gating: one wave per token (also emits xb = bf16(x)) ----------------
__global__ void k_gate(const float* __restrict__ x, const float* __restrict__ gw,
                       const float* __restrict__ gb, unsigned short* __restrict__ xb,
                       int* __restrict__ sel, int* __restrict__ counts) {
    const int wid = threadIdx.x >> 6, lane = threadIdx.x & 63;
    const int tok = blockIdx.x * 4 + wid;
    const float* xr = x + (long)tok * DDIM;
    unsigned short* xbr = xb + (long)tok * DDIM;
    float s[NEXP];
#pragma unroll
    for (int e = 0; e < NEXP; ++e) s[e] = 0.f;
    for (int it = 0; it < DDIM / 64; ++it) {
        const int kk = it * 64 + lane;
        const float xv = xr[kk];
        xbr[kk] = f2bf(xv);
        const float4* g4 = (const float4*)(gw + (long)kk * NEXP);
        const float4 g0 = g4[0], g1 = g4[1];
        s[0] += xv * g0.x; s[1] += xv * g0.y; s[2] += xv * g0.z; s[3] += xv * g0.w;
        s[4] += xv * g1.x; s[5] += xv * g1.y; s[6] += xv * g1.z; s[7] += xv * g1.w;
    }
#pragma unroll
    for (int e = 0; e < NEXP; ++e)
        for (int off = 32; off > 0; off >>= 1)
            s[e] += __shfl_down(s[e], off);
    if (lane == 0) {
        float best = s[0] + gb[0]; int bi = 0;
#pragma unroll
        for (int e = 1; e < NEXP; ++e) {
            const float v = s[e] + gb[e];
            if (v > best) { best = v; bi = e; }   // strict > keeps lowest index (np.argmax)
        }
        sel[tok] = bi;
        atomicAdd(&counts[bi], 1);
    }
}

// ---------------- fill token lists + scan + live-tile tables (k_scan absorbed) ---------
__global__ void k_fill(const int* __restrict__ sel, const int* __restrict__ counts,
                       int* __restrict__ cur, int* __restrict__ offs,
                       int* __restrict__ list, int* __restrict__ t0,
                       int* __restrict__ t1, float* __restrict__ laux) {
    const int t = blockIdx.x * blockDim.x + threadIdx.x;
    if (t < NTOK) {
        const int e = sel[t];
        int off_e = 0;
#pragma unroll
        for (int j = 0; j < NEXP; ++j) off_e += (j < e) ? counts[j] : 0;  // no array (rule #20)
        list[off_e + atomicAdd(&cur[e], 1)] = t;
    }
    if (t == 0) {
        int o = 0;
        for (int e = 0; e < NEXP; ++e) { offs[e] = o; o += counts[e]; }
        offs[NEXP] = o;
        int i0 = 0;
        for (int e = 0; e < NEXP; ++e)
            for (int m = 0; m < counts[e]; m += 128) t0[i0++] = (e << 16) | m;
        while (i0 < T0MAX) t0[i0++] = -1;
        int i1 = 0;
        for (int e = 0; e < NEXP; ++e)
            for (int m = 0; m < counts[e]; m += 64) t1[i1++] = (e << 16) | m;
        while (i1 < T1MAX) t1[i1++] = -1;
        laux[0] = 0.f;
    }
}

// ---------------- W [e][K][NC] f32 -> Wt [e][NC][K] bf16 (transpose-convert) ----------------
template<int K, int NC>
__global__ __launch_bounds__(256) void k_cvt_w(const float* __restrict__ W,
                                               unsigned short* __restrict__ Wt) {
    __shared__ unsigned short T[64 * 68];   // [n][k], stride 68 breaks bank conflicts
    const int ktiles = K / 64;
    const int e  = blockIdx.y / ktiles;
    const int k0 = (blockIdx.y % ktiles) * 64;
    const int n0 = blockIdx.x * 64;
    const float* src = W + (long)e * K * NC + (long)k0 * NC + n0;
    const int tid = threadIdx.x;
#pragma unroll
    for (int i = 0; i < 4; ++i) {
        const int idx = tid + i * 256;
        const int k = idx >> 4, c4 = (idx & 15) * 4;
        const float4 v = *(const float4*)(src + (long)k * NC + c4);
        T[(c4 + 0) * 68 + k] = f2bf(v.x);
        T[(c4 + 1) * 68 + k] = f2bf(v.y);
        T[(c4 + 2) * 68 + k] = f2bf(v.z);
        T[(c4 + 3) * 68 + k] = f2bf(v.w);
    }
    __syncthreads();
    unsigned short* dst = Wt + (long)e * NC * K + (long)n0 * K + k0;
#pragma unroll
    for (int i = 0; i < 2; ++i) {
        const int idx = tid + i * 256;
        const int n = idx >> 3, c8 = (idx & 7) * 8;
        *(ushort4*)(dst + (long)n * K + c8)     = *(const ushort4*)&T[n * 68 + c8];
        *(ushort4*)(dst + (long)n * K + c8 + 4) = *(const ushort4*)&T[n * 68 + c8 + 4];
    }
}

// ---------------- grouped GEMM: m97 structure + COMPACT LIVE-TILE GRID ----------------
// blockIdx.y indexes a packed table of live (e, m0) tiles -> ~95% live dispatch stream,
// so 4-6 blocks co-resident per CU provide the cross-block latency hiding (m114).
// Single-buffered LDS, XOR swizzle via pre-swizzled global source, global_load_lds w=16.
// MODE 0 epilogue: LDS re-tile (stride-136 shorts = 272B, 16B-aligned) -> 16B stores.
template<int MODE, int BM_, int BN_>
__global__ __launch_bounds__(256) void k_gemm(
        const unsigned short* __restrict__ Ain,
        const unsigned short* __restrict__ Wt,
        const float* __restrict__ bias,
        unsigned short* __restrict__ Hout, float* __restrict__ Yout,
        const int* __restrict__ counts, const int* __restrict__ offs,
        const int* __restrict__ list, const int* __restrict__ ttab) {
    static_assert(BM_ % 32 == 0 && BN_ % 32 == 0, "tile");
    constexpr int K  = (MODE == 0) ? DDIM : HDIM;
    constexpr int NC = (MODE == 0) ? HDIM : DDIM;
    constexpr int NT = K / BK;
    constexpr int FM = BM_ / 32;
    constexpr int FN = BN_ / 32;
    constexpr int LA = BM_ / 32;   // A loads per thread per tile
    constexpr int LB = BN_ / 32;
    constexpr int EP = 136;        // epilogue re-tile stride (shorts): >=BN_(128), 16B-mult
    constexpr int STAGE_SH = BM_ * 64 + BN_ * 64;
    constexpr int SH_SZ = (MODE == 0 && BM_ * EP > STAGE_SH) ? BM_ * EP : STAGE_SH;

    const int code = ttab[blockIdx.y];
    if (code < 0) return;
    const int e  = code >> 16;
    const int m0 = code & 0xFFFF;
    const int cnt  = counts[e];
    const int base = offs[e];
    const int n0   = blockIdx.x * BN_;

    __shared__ __align__(16) unsigned short sh[SH_SZ];
    unsigned short* Asb = sh;
    unsigned short* Btb = sh + BM_ * 64;

    const int tid  = threadIdx.x;
    const int lane = tid & 63, wid = tid >> 6;
    const int lr = lane >> 3, lc = lane & 7;
    const int sb = (lc * 16) ^ (lr << 4);        // pre-swizzled source byte offset

    const unsigned short* pA[LA];
#pragma unroll
    for (int i = 0; i < LA; ++i) {
        const int r = wid * (BM_ / 4) + i * 8 + lr;
        int rr = m0 + r; if (rr >= cnt) rr = cnt - 1;
        const long grow = (MODE == 0) ? (long)list[base + rr] : (long)(base + rr);
        pA[i] = (const unsigned short*)((const char*)(Ain + grow * K) + sb);
    }
    const unsigned short* We = Wt + (long)e * NC * K;
    const unsigned short* pB[LB];
#pragma unroll
    for (int i = 0; i < LB; ++i) {
        const int r = wid * (BN_ / 4) + i * 8 + lr;
        pB[i] = (const unsigned short*)((const char*)(We + (long)(n0 + r) * K) + sb);
    }

    const int wm = (wid >> 1) * (BM_ / 2);
    const int wn = (wid & 1) * 64;
    const int hk = 16 * (lane >> 4);

    const f32x4 zero4 = {0.f, 0.f, 0.f, 0.f};
    f32x4 acc[FM][FN];
#pragma unroll
    for (int i = 0; i < FM; ++i)
#pragma unroll
        for (int j = 0; j < FN; ++j) acc[i][j] = zero4;

    for (int t = 0; t < NT; ++t) {
        __syncthreads();   // prior-iter readers done
#pragma unroll
        for (int i = 0; i < LA; ++i)
            __builtin_amdgcn_global_load_lds((gas_t*)(pA[i] + t * 64),
                (las_t*)(Asb + (wid * (BM_ / 4) + i * 8) * 64), 16, 0, 0);
#pragma unroll
        for (int i = 0; i < LB; ++i)
            __builtin_amdgcn_global_load_lds((gas_t*)(pB[i] + t * 64),
                (las_t*)(Btb + (wid * (BN_ / 4) + i * 8) * 64), 16, 0, 0);
        __syncthreads();   // staging complete
#pragma unroll
        for (int kk = 0; kk < BK; kk += 32) {
            bf16x8 a[FM], b[FN];
#pragma unroll
            for (int mf = 0; mf < FM; ++mf) {
                const int r  = wm + mf * 16 + (lane & 15);
                const int kb = (2 * kk + hk) ^ ((r & 7) << 4);
                a[mf] = *(const bf16x8*)((const char*)Asb + r * 128 + kb);
            }
#pragma unroll
            for (int nf = 0; nf < FN; ++nf) {
                const int cc = wn + nf * 16 + (lane & 15);
                const int kb = (2 * kk + hk) ^ ((cc & 7) << 4);
                b[nf] = *(const bf16x8*)((const char*)Btb + cc * 128 + kb);
            }
            __builtin_amdgcn_s_setprio(1);
#pragma unroll
            for (int mf = 0; mf < FM; ++mf)
#pragma unroll
                for (int nf = 0; nf < FN; ++nf)
                    acc[mf][nf] = __builtin_amdgcn_mfma_f32_16x16x32_bf16(
                        a[mf], b[nf], acc[mf][nf], 0, 0, 0);
            __builtin_amdgcn_s_setprio(0);
        }
    }

    // ---- epilogue ----
    if constexpr (MODE == 0) {
        // bias+gelu -> bf16 tile in LDS ([BM][EP=136] shorts, 272B rows, 16B-aligned),
        // then 16B coalesced stores: thread -> (row = tid>>1, 64-col half).
        __syncthreads();   // all MFMA reads of sh done
#pragma unroll
        for (int nf = 0; nf < FN; ++nf) {
            const int cl = wn + nf * 16 + (lane & 15);
            const float bv = bias[(long)e * NC + n0 + cl];
#pragma unroll
            for (int mf = 0; mf < FM; ++mf) {
#pragma unroll
                for (int ri = 0; ri < 4; ++ri) {
                    const int rl = wm + mf * 16 + (lane >> 4) * 4 + ri;
                    sh[rl * EP + cl] = f2bf(gelu_f(acc[mf][nf][ri] + bv));
                }
            }
        }
        __syncthreads();
        const int row = tid >> 1, ch = (tid & 1) * 64;
        if (m0 + row < cnt) {
            char* dst = (char*)(Hout + (long)(base + m0 + row) * HDIM + n0 + ch);
            const char* srcp = (const char*)sh + row * (EP * 2) + ch * 2;
#pragma unroll
            for (int j = 0; j < 4; ++j) {
                const int4 v0 = *(const int4*)(srcp + j * 32);
                const int4 v1 = *(const int4*)(srcp + j * 32 + 16);
                *(int4*)(dst + j * 32)      = v0;
                *(int4*)(dst + j * 32 + 16) = v1;
            }
        }
    } else {
#pragma unroll
        for (int nf = 0; nf < FN; ++nf) {
            const int coln = n0 + wn + nf * 16 + (lane & 15);
            const float bv = bias[(long)e * NC + coln];
#pragma unroll
            for (int mf = 0; mf < FM; ++mf) {
                const int rb = m0 + wm + mf * 16 + (lane >> 4) * 4;
#pragma unroll
                for (int ri = 0; ri < 4; ++ri) {
                    const int row = rb + ri;
                    if (row < cnt)
                        Yout[(long)list[base + row] * DDIM + coln] = acc[mf][nf][ri] + bv;
                }
            }
        }
    }
}

extern "C" void kernel_launch(void* const* d_in, const int* in_sizes, int n_in,
                              void* d_out, int out_size, void* d_ws, size_t ws_size,
                              hipStream_t stream) {
    const float* x      = (const float*)d_in[0];
    const float* gate_w = (const float*)d_in[1];
    const float* gate_b = (const float*)d_in[2];
    const float* w1     = (const float*)d_in[3];
    const float* b1     = (const float*)d_in[4];
    const float* w2     = (const float*)d_in[5];
    const float* b2     = (const float*)d_in[6];
    float* out = (float*)d_out;

    // workspace layout
    char* ws = (char*)d_ws;
    int* counts  = (int*)(ws);                 // 8
    int* cur     = (int*)(ws + 128);           // 8
    int* offs    = (int*)(ws + 256);           // 9
    int* t0      = (int*)(ws + 512);           // T0MAX
    int* t1      = (int*)(ws + 768);           // T1MAX
    int* sel     = (int*)(ws + 4096);          // 4096
    int* list    = (int*)(ws + 20480);         // 4096
    unsigned short* xb  = (unsigned short*)(ws + 65536);                      // 8 MB
    unsigned short* Hws = (unsigned short*)(ws + 65536 + 8388608);            // 33.5 MB
    unsigned short* Wtb = (unsigned short*)(ws + 65536 + 8388608 + 33554432); // 67 MB (W1t then W2t)
    const size_t WS_NEEDED = 65536 + 8388608 + 33554432 + 67108864;
    if (ws_size < WS_NEEDED) return;  // deterministic fail, no corruption

    hipMemsetAsync(ws, 0, 256, stream);   // counts + cur
    k_gate<<<NTOK / 4, 256, 0, stream>>>(x, gate_w, gate_b, xb, sel, counts);
    k_fill<<<(NTOK + 255) / 256, 256, 0, stream>>>(sel, counts, cur, offs, list, t0, t1,
                                                   out + (long)NTOK * DDIM);

    // W1t = transpose-convert(w1); FFN up+gelu: 128x128 tiles, compact grid
    k_cvt_w<DDIM, HDIM><<<dim3(HDIM / 64, NEXP * (DDIM / 64)), 256, 0, stream>>>(w1, Wtb);
    k_gemm<0, 128, 128><<<dim3(HDIM / 128, T0MAX), 256, 0, stream>>>(
        xb, Wtb, b1, Hws, nullptr, counts, offs, list, t0);

    // W2t = transpose-convert(w2) into same buffer; FFN down: 64x128 tiles, compact grid
    k_cvt_w<HDIM, DDIM><<<dim3(DDIM / 64, NEXP * (HDIM / 64)), 256, 0, stream>>>(w2, Wtb);
    k_gemm<1, 64, 128><<<dim3(DDIM / 128, T1MAX), 256, 0, stream>>>(
        Hws, Wtb, b2, nullptr, out, counts, offs, list, t1);
}